// Round 1
// baseline (1332.213 us; speedup 1.0000x reference)
//
#include <hip/hip_runtime.h>

// Problem constants (fixed by the reference: B=4, MAX_LEN=4096, H=32, D=128, Q_LEN=1)
constexpr long long N_ELEM  = 4LL * 4096 * 32 * 128; // 67,108,864 per K or V tensor
constexpr long long N_ROWS  = 4LL * 4096 * 32;       // 524,288 rows of D=128
constexpr long long MASK_N  = 4LL * 4096;            // 16,384
constexpr long long SCALE_N = N_ROWS;                // 524,288

// d_out float32 layout (flat, return order):
//   [0, N)                  key_out
//   [N, 2N)                 value_out
//   [2N, 2N+MASK)           attn_mask_out (bool as 0.0/1.0)
//   [2N+MASK, 3N+MASK)      key_q (int8 value as float)
//   [3N+MASK, +SCALE)       key_scale
//   [.., +N)                value_q
//   [.., +SCALE)            value_scale

// Native ext_vector type so __builtin_nontemporal_{load,store} accepts it.
typedef float vf4 __attribute__((ext_vector_type(4)));

__global__ __launch_bounds__(256) void kv_update_quant_kernel(
    const float* __restrict__ cached_key,
    const float* __restrict__ cached_value,
    const float* __restrict__ key_new,     // (B,1,H,D)
    const float* __restrict__ value_new,   // (B,1,H,D)
    const int*   __restrict__ cache_index,
    float* __restrict__ out)
{
    const int cur  = cache_index[0];
    const int hw   = threadIdx.x >> 5;   // half-wave id 0..7
    const int lane = threadIdx.x & 31;

    // Each half-wave owns 4 CONSECUTIVE rows (r0..r0+3). r0 is a multiple of 4,
    // so all 4 rows share (b, s) and differ only in h (h0..h0+3) -> one branch,
    // one base address, and a 2 KB contiguous burst per stream per half-wave.
    const long long row0 = (((long long)blockIdx.x * 8 + hw) << 2);
    const bool isv = row0 >= N_ROWS;               // value-tensor half of the row space
    const long long r0 = isv ? row0 - N_ROWS : row0;

    const int h0 = (int)(r0 & 31);
    const int s  = (int)((r0 >> 5) & 4095);
    const long long b = r0 >> 17;

    // dynamic_update_slice: rows at s == cache_index come from the new K/V.
    const float* src;
    if (s == cur) {
        src = (isv ? value_new : key_new) + (((b << 5) + (long long)h0) << 7);
    } else {
        src = (isv ? cached_value : cached_key) + (r0 << 7);
    }
    src += (lane << 2);

    // Issue all 4 row-loads back-to-back (nt: pure streaming, no reuse).
    vf4 v[4];
#pragma unroll
    for (int j = 0; j < 4; ++j)
        v[j] = __builtin_nontemporal_load(reinterpret_cast<const vf4*>(src + (j << 7)));

    // Per-row max|x| over the 128-row: 4 local, then 5-step xor-shuffle across the
    // half-wave (masks <= 16 keep the two 32-lane halves independent). The 4 chains
    // are independent and pipeline.
    float sc[4];
#pragma unroll
    for (int j = 0; j < 4; ++j) {
        float m = fmaxf(fmaxf(fabsf(v[j].x), fabsf(v[j].y)),
                        fmaxf(fabsf(v[j].z), fabsf(v[j].w)));
#pragma unroll
        for (int off = 16; off >= 1; off >>= 1)
            m = fmaxf(m, __shfl_xor(m, off));
        // IEEE f32 div + rintf (round-half-even) matches jnp round/div.
        sc[j] = fmaxf(m / 127.0f, 1e-8f);
    }

    float* out_p = out + (isv ? N_ELEM : 0) + (r0 << 7) + (lane << 2);
    float* q_p   = out + 2 * N_ELEM + MASK_N + (isv ? (N_ELEM + SCALE_N) : 0)
                   + (r0 << 7) + (lane << 2);

#pragma unroll
    for (int j = 0; j < 4; ++j) {
        __builtin_nontemporal_store(v[j], reinterpret_cast<vf4*>(out_p + (j << 7)));
        vf4 q;
        q.x = fminf(fmaxf(rintf(v[j].x / sc[j]), -128.0f), 127.0f);
        q.y = fminf(fmaxf(rintf(v[j].y / sc[j]), -128.0f), 127.0f);
        q.z = fminf(fmaxf(rintf(v[j].z / sc[j]), -128.0f), 127.0f);
        q.w = fminf(fmaxf(rintf(v[j].w / sc[j]), -128.0f), 127.0f);
        __builtin_nontemporal_store(q, reinterpret_cast<vf4*>(q_p + (j << 7)));
    }

    // 4 consecutive per-row scales -> one 16 B nt store from lane 0 (no partial-line RMW).
    if (lane == 0) {
        float* s_p = out + 3 * N_ELEM + MASK_N + (isv ? (N_ELEM + SCALE_N) : 0) + r0;
        vf4 sv;
        sv.x = sc[0]; sv.y = sc[1]; sv.z = sc[2]; sv.w = sc[3];
        __builtin_nontemporal_store(sv, reinterpret_cast<vf4*>(s_p));
    }
}

__global__ __launch_bounds__(256) void mask_kernel(
    const int* __restrict__ attention_mask,   // bool input, harness passes integer
    const int* __restrict__ cache_index,
    float* __restrict__ out_mask)             // 16,384 floats at out + 2N
{
    const int i = blockIdx.x * 256 + threadIdx.x;
    if (i < (int)MASK_N) {
        const int pos = i & 4095;
        const bool pad = pos < (cache_index[0] + 1);   // arange(max_len) < cur + num_updated
        const bool am  = attention_mask[i] != 0;
        out_mask[i] = (pad && am) ? 1.0f : 0.0f;
    }
}

extern "C" void kernel_launch(void* const* d_in, const int* in_sizes, int n_in,
                              void* d_out, int out_size, void* d_ws, size_t ws_size,
                              hipStream_t stream) {
    const float* cached_key   = (const float*)d_in[0];
    const float* cached_value = (const float*)d_in[1];
    const float* key_new      = (const float*)d_in[2];
    const float* value_new    = (const float*)d_in[3];
    const int*   attn_mask    = (const int*)d_in[4];
    const int*   cache_index  = (const int*)d_in[5];
    float* out = (float*)d_out;

    // 2 tensors x 524,288 rows; 8 half-waves/block x 4 rows each = 32 rows/block
    // -> 1,048,576 / 32 = 32,768 blocks
    kv_update_quant_kernel<<<32768, 256, 0, stream>>>(
        cached_key, cached_value, key_new, value_new, cache_index, out);

    mask_kernel<<<(int)(MASK_N / 256), 256, 0, stream>>>(
        attn_mask, cache_index, out + 2 * N_ELEM);
}